// Round 2
// baseline (692.499 us; speedup 1.0000x reference)
//
#include <hip/hip_runtime.h>

// EnvironmentalAugmentations: pink = AR(1) scan of white noise (a=0.99, b=0.01),
// mixed = waveform + 0.05*pink, out = mixed / max(|mixed|) if max > 1 else mixed.
// Shapes: (256 channels, 220500 samples), f32 in / f32 out.
//
// Chunked-independence: 0.99^1024 = 3.4e-5, so each 8192-sample chunk is computed
// independently with a 1024-sample warm-up (truncation error < 1e-6 in output).
// No LDS staging: each thread owns 32 contiguous samples in registers (R1 showed
// the LDS version latency-bound at 41% occupancy, 12% VALU, 2.65 TB/s).

#define TLEN 220500
#define CHANNELS 256

constexpr int CL   = 8192;          // samples per block
constexpr int H    = 1024;          // warm-up history
constexpr int NT   = 256;           // threads per block
constexpr int SEG  = 32;            // CL / NT samples per thread
constexpr int NCHUNK = (TLEN + CL - 1) / CL;   // 27

constexpr float AC = 0.99f;
constexpr float BC = 0.01f;
constexpr float NL = 0.05f;

constexpr double dpow(double a, int n) { double r = 1.0; for (int i = 0; i < n; ++i) r *= a; return r; }

// Scan-step multipliers (constant-A Hillis-Steele: pB = A^d * partner + pB gives
// the geometric-weighted prefix sum exactly).
constexpr float SP0 = (float)dpow(0.99, 32 * 1);    // main scan, offset 1
constexpr float SP1 = (float)dpow(0.99, 32 * 2);
constexpr float SP2 = (float)dpow(0.99, 32 * 4);
constexpr float SP3 = (float)dpow(0.99, 32 * 8);
constexpr float SP4 = (float)dpow(0.99, 32 * 16);
constexpr float SP5 = (float)dpow(0.99, 32 * 32);
constexpr float WP0 = (float)dpow(0.99, 4 * 1);     // warm-up scan (4 samples/thread)
constexpr float WP1 = (float)dpow(0.99, 4 * 2);
constexpr float WP2 = (float)dpow(0.99, 4 * 4);
constexpr float WP3 = (float)dpow(0.99, 4 * 8);
constexpr float WP4 = (float)dpow(0.99, 4 * 16);
constexpr float WP5 = (float)dpow(0.99, 4 * 32);
constexpr float AWW = (float)dpow(0.99, 256);       // warm-up wave total A (4*64)
// log2(0.99^32) for exp2f-based per-thread decay factors
constexpr float L2ASEG = -0.4639862302435683f;      // 32 * log2(0.99)

__global__ void init_max_kernel(unsigned int* gmax) { *gmax = 0u; }

__global__ __launch_bounds__(NT, 6)
void pink_mix_kernel(const float* __restrict__ waveform,
                     const float* __restrict__ white,
                     float* __restrict__ out,
                     unsigned int* __restrict__ gmax)
{
    __shared__ float sB[4];     // main-scan wave totals (B)
    __shared__ float swB[4];    // warm-up wave totals (B)
    __shared__ float sM[4];     // per-wave max
    __shared__ float sW0;       // first white sample of chunk (chunk 0 entry state)

    const int chunk = blockIdx.x;
    const int ch    = blockIdx.y;
    const int c0    = chunk * CL;
    const size_t rowoff = (size_t)ch * TLEN;
    const float* __restrict__ wrow = white + rowoff;
    const float* __restrict__ arow = waveform + rowoff;
    float* __restrict__ orow = out + rowoff;

    const int tid  = threadIdx.x;
    const int lane = tid & 63;
    const int wv   = tid >> 6;
    const int s0   = c0 + tid * SEG;     // this thread's first sample

    // ---- direct load: 32 contiguous samples per thread (8x float4) ----
    float w[SEG];
    #pragma unroll
    for (int i = 0; i < SEG / 4; ++i) {
        int g = s0 + 4 * i;
        float4 v = make_float4(0.f, 0.f, 0.f, 0.f);
        if (g < TLEN) v = *reinterpret_cast<const float4*>(wrow + g);   // TLEN % 4 == 0
        w[4 * i]     = v.x;
        w[4 * i + 1] = v.y;
        w[4 * i + 2] = v.z;
        w[4 * i + 3] = v.w;
    }

    // ---- warm-up: total geometric sum over [c0-H, c0), entry state 0 ----
    if (chunk > 0) {
        float4 v = *reinterpret_cast<const float4*>(wrow + (c0 - H) + 4 * tid);
        float f = 0.f;
        f = fmaf(AC, f, BC * v.x);
        f = fmaf(AC, f, BC * v.y);
        f = fmaf(AC, f, BC * v.z);
        f = fmaf(AC, f, BC * v.w);
        float pB = f;
        { float o = __shfl_up(pB, 1,  64); if (lane >= 1)  pB = fmaf(WP0, o, pB); }
        { float o = __shfl_up(pB, 2,  64); if (lane >= 2)  pB = fmaf(WP1, o, pB); }
        { float o = __shfl_up(pB, 4,  64); if (lane >= 4)  pB = fmaf(WP2, o, pB); }
        { float o = __shfl_up(pB, 8,  64); if (lane >= 8)  pB = fmaf(WP3, o, pB); }
        { float o = __shfl_up(pB, 16, 64); if (lane >= 16) pB = fmaf(WP4, o, pB); }
        { float o = __shfl_up(pB, 32, 64); if (lane >= 32) pB = fmaf(WP5, o, pB); }
        if (lane == 63) swB[wv] = pB;
    }

    // ---- main local scan (entry 0) + wave B-scan ----
    float f = 0.f;
    #pragma unroll
    for (int k = 0; k < SEG; ++k)
        f = fmaf(AC, f, BC * w[k]);
    float pB = f;
    { float o = __shfl_up(pB, 1,  64); if (lane >= 1)  pB = fmaf(SP0, o, pB); }
    { float o = __shfl_up(pB, 2,  64); if (lane >= 2)  pB = fmaf(SP1, o, pB); }
    { float o = __shfl_up(pB, 4,  64); if (lane >= 4)  pB = fmaf(SP2, o, pB); }
    { float o = __shfl_up(pB, 8,  64); if (lane >= 8)  pB = fmaf(SP3, o, pB); }
    { float o = __shfl_up(pB, 16, 64); if (lane >= 16) pB = fmaf(SP4, o, pB); }
    { float o = __shfl_up(pB, 32, 64); if (lane >= 32) pB = fmaf(SP5, o, pB); }
    float eB = __shfl_up(pB, 1, 64);                 // lane-exclusive B
    if (lane == 0) eB = 0.f;
    if (lane == 63) sB[wv] = pB;
    if (tid == 0) sW0 = w[0];
    __syncthreads();

    // chunk entry state: warm-up total, or w[0] for chunk 0 (a*w0 + b*w0 = w0)
    float fin;
    if (chunk > 0) {
        float t = swB[0];
        t = fmaf(AWW, t, swB[1]);
        t = fmaf(AWW, t, swB[2]);
        t = fmaf(AWW, t, swB[3]);
        fin = t;
    } else {
        fin = sW0;
    }

    // wave-exclusive prefix over wave totals (constant wave A = 0.99^2048)
    constexpr float AW = (float)dpow(0.99, 2048);
    float wB = 0.f;
    for (int u = 0; u < wv; ++u) wB = fmaf(AW, wB, sB[u]);

    // entry state for this thread's segment:
    // fe = A^(32*tid)*fin + A^(32*lane)*wB + eB
    const float fe = fmaf(__builtin_exp2f((float)tid  * L2ASEG), fin,
                     fmaf(__builtin_exp2f((float)lane * L2ASEG), wB, eB));

    // ---- rescan with correct entry state, fused mix + store + max ----
    f = fe;
    float mx = 0.f;
    #pragma unroll
    for (int i = 0; i < SEG / 4; ++i) {
        int g = s0 + 4 * i;
        if (g < TLEN) {
            float4 a = *reinterpret_cast<const float4*>(arow + g);
            float4 m;
            f = fmaf(AC, f, BC * w[4 * i]);     m.x = fmaf(NL, f, a.x);
            f = fmaf(AC, f, BC * w[4 * i + 1]); m.y = fmaf(NL, f, a.y);
            f = fmaf(AC, f, BC * w[4 * i + 2]); m.z = fmaf(NL, f, a.z);
            f = fmaf(AC, f, BC * w[4 * i + 3]); m.w = fmaf(NL, f, a.w);
            *reinterpret_cast<float4*>(orow + g) = m;
            mx = fmaxf(mx, fmaxf(fmaxf(fabsf(m.x), fabsf(m.y)),
                                 fmaxf(fabsf(m.z), fabsf(m.w))));
        }
    }

    // ---- block max -> global atomic ----
    #pragma unroll
    for (int d = 32; d >= 1; d >>= 1)
        mx = fmaxf(mx, __shfl_xor(mx, d, 64));
    if (lane == 0) sM[wv] = mx;
    __syncthreads();
    if (tid == 0) {
        float m = fmaxf(fmaxf(sM[0], sM[1]), fmaxf(sM[2], sM[3]));
        atomicMax(gmax, __float_as_uint(m));   // values >= 0: uint order == float order
    }
}

__global__ __launch_bounds__(256)
void scale_kernel(float* __restrict__ out, const unsigned int* __restrict__ gmax, int n4)
{
    const float m = __uint_as_float(*gmax);
    const float s = (m > 1.0f) ? (1.0f / m) : 1.0f;
    float4* p = reinterpret_cast<float4*>(out);
    int i = blockIdx.x * blockDim.x + threadIdx.x;
    const int stride = gridDim.x * blockDim.x;
    for (; i < n4; i += stride) {
        float4 v = p[i];
        v.x *= s; v.y *= s; v.z *= s; v.w *= s;
        p[i] = v;
    }
}

extern "C" void kernel_launch(void* const* d_in, const int* in_sizes, int n_in,
                              void* d_out, int out_size, void* d_ws, size_t ws_size,
                              hipStream_t stream)
{
    const float* waveform = (const float*)d_in[0];
    const float* white    = (const float*)d_in[1];
    float* out            = (float*)d_out;
    unsigned int* gmax    = (unsigned int*)d_ws;

    hipLaunchKernelGGL(init_max_kernel, dim3(1), dim3(1), 0, stream, gmax);

    dim3 grid(NCHUNK, CHANNELS);           // 27 x 256 blocks
    hipLaunchKernelGGL(pink_mix_kernel, grid, dim3(NT), 0, stream,
                       waveform, white, out, gmax);

    const int n4 = out_size / 4;           // 14,112,000 float4s
    hipLaunchKernelGGL(scale_kernel, dim3(3072), dim3(256), 0, stream,
                       out, gmax, n4);
}

// Round 3
// 234.770 us; speedup vs baseline: 2.9497x; 2.9497x over previous
//
#include <hip/hip_runtime.h>

// EnvironmentalAugmentations: pink = AR(1) scan of white noise (a=0.99, b=0.01),
// mixed = waveform + 0.05*pink, out = mixed / max(|mixed|) if max > 1 else mixed.
// Shapes: (256 channels, 220500 samples), f32 in / f32 out.
//
// Chunked-independence: 0.99^1024 = 3.4e-5 -> each 8192-sample chunk computed
// independently with a 1024-sample warm-up (truncation error < 1e-6 in output).
//
// R1: LDS-staged version -> latency-bound (41% occ, 12% VALU, 175 us).
// R2: per-thread-contiguous loads -> uncoalesced, FETCH 235 MB -> 1.68 GB, 625 us.
// R3: coalesced float4 ownership made directly scannable: chunk = 8 superblocks
//     of 1024; thread owns samples [4*tid, 4*tid+4) of each superblock (exactly
//     the coalesced float4 at index i*NT+tid). Registers only; LDS = 37 floats.

#define TLEN 220500
#define CHANNELS 256

constexpr int CL   = 8192;          // samples per block
constexpr int NT   = 256;           // threads per block
constexpr int NSB  = 8;             // superblocks per chunk (1024 samples each)
constexpr int NCHUNK = (TLEN + CL - 1) / CL;   // 27

constexpr float AC = 0.99f;
constexpr float BC = 0.01f;
constexpr float NL = 0.05f;

constexpr double dpow(double a, int n) { double r = 1.0; for (int i = 0; i < n; ++i) r *= a; return r; }

// Geometric Hillis-Steele step multipliers, 4-sample granularity: 0.99^(4d)
constexpr float WP0 = (float)dpow(0.99, 4 * 1);
constexpr float WP1 = (float)dpow(0.99, 4 * 2);
constexpr float WP2 = (float)dpow(0.99, 4 * 4);
constexpr float WP3 = (float)dpow(0.99, 4 * 8);
constexpr float WP4 = (float)dpow(0.99, 4 * 16);
constexpr float WP5 = (float)dpow(0.99, 4 * 32);
constexpr float A256  = (float)dpow(0.99, 256);    // wave (64 lanes x 4 samples)
constexpr float A1024 = (float)dpow(0.99, 1024);   // superblock
constexpr float L2A4   = -0.05799827878044602f;    // 4   * log2(0.99)
constexpr float L2A256 = -3.7118898419485456f;     // 256 * log2(0.99)

__global__ void init_max_kernel(unsigned int* gmax) { *gmax = 0u; }

__device__ __forceinline__ float wave_scan4(float f, int lane) {
    // inclusive geometric scan across 64 lanes, 4 samples per lane
    { float o = __shfl_up(f, 1,  64); if (lane >= 1)  f = fmaf(WP0, o, f); }
    { float o = __shfl_up(f, 2,  64); if (lane >= 2)  f = fmaf(WP1, o, f); }
    { float o = __shfl_up(f, 4,  64); if (lane >= 4)  f = fmaf(WP2, o, f); }
    { float o = __shfl_up(f, 8,  64); if (lane >= 8)  f = fmaf(WP3, o, f); }
    { float o = __shfl_up(f, 16, 64); if (lane >= 16) f = fmaf(WP4, o, f); }
    { float o = __shfl_up(f, 32, 64); if (lane >= 32) f = fmaf(WP5, o, f); }
    return f;
}

__global__ __launch_bounds__(NT, 6)
void pink_mix_kernel(const float* __restrict__ waveform,
                     const float* __restrict__ white,
                     float* __restrict__ out,
                     unsigned int* __restrict__ gmax)
{
    __shared__ float sB[NSB + 1][4];   // wave totals: 8 main superblocks + warm-up
    __shared__ float sM[4];            // per-wave max
    __shared__ float sW0;              // first white sample of chunk

    const int chunk = blockIdx.x;
    const int ch    = blockIdx.y;
    const int c0    = chunk * CL;
    const size_t rowoff = (size_t)ch * TLEN;
    const float* __restrict__ wrow = white + rowoff;
    const float* __restrict__ arow = waveform + rowoff;
    float* __restrict__ orow = out + rowoff;

    const int tid  = threadIdx.x;
    const int lane = tid & 63;
    const int wv   = tid >> 6;

    // ---- coalesced load: 8 float4s, thread owns [i*1024 + 4*tid, +4) ----
    float w[4 * NSB];
    #pragma unroll
    for (int i = 0; i < NSB; ++i) {
        int g = c0 + i * 1024 + 4 * tid;
        float4 v = make_float4(0.f, 0.f, 0.f, 0.f);
        if (g < TLEN) v = *reinterpret_cast<const float4*>(wrow + g);  // TLEN%4==0
        w[4 * i]     = v.x;
        w[4 * i + 1] = v.y;
        w[4 * i + 2] = v.z;
        w[4 * i + 3] = v.w;
    }

    // ---- per-superblock: 4-sample serial + wave scan; lane-excl kept in regs ----
    float eB[NSB];
    #pragma unroll
    for (int i = 0; i < NSB; ++i) {
        float f = BC * w[4 * i];
        f = fmaf(AC, f, BC * w[4 * i + 1]);
        f = fmaf(AC, f, BC * w[4 * i + 2]);
        f = fmaf(AC, f, BC * w[4 * i + 3]);
        float pB = wave_scan4(f, lane);
        float e  = __shfl_up(pB, 1, 64);
        eB[i] = (lane == 0) ? 0.f : e;
        if (lane == 63) sB[i][wv] = pB;
    }

    // ---- warm-up superblock [c0-1024, c0) (chunk>0; always in-bounds) ----
    if (chunk > 0) {
        float4 v = *reinterpret_cast<const float4*>(wrow + (c0 - 1024) + 4 * tid);
        float f = BC * v.x;
        f = fmaf(AC, f, BC * v.y);
        f = fmaf(AC, f, BC * v.z);
        f = fmaf(AC, f, BC * v.w);
        float pB = wave_scan4(f, lane);
        if (lane == 63) sB[NSB][wv] = pB;
    }
    if (tid == 0) sW0 = w[0];
    __syncthreads();

    // ---- chunk entry state ----
    // chunk 0: f_entry = w[0] works because a*w0 + b*w0 = w0 reproduces pink[0]=w0.
    float E;
    if (chunk > 0) {
        float t = sB[NSB][0];
        t = fmaf(A256, t, sB[NSB][1]);
        t = fmaf(A256, t, sB[NSB][2]);
        t = fmaf(A256, t, sB[NSB][3]);
        E = t;
    } else {
        E = sW0;
    }

    // per-thread decay factors
    const float D4L = __builtin_exp2f((float)lane * L2A4);   // 0.99^(4*lane)
    const float DW  = __builtin_exp2f((float)wv   * L2A256); // 0.99^(256*wv)

    // ---- per-superblock: entry state, rescan, fused mix + store + max ----
    float mx = 0.f;
    #pragma unroll
    for (int i = 0; i < NSB; ++i) {
        const float b0 = sB[i][0], b1 = sB[i][1], b2 = sB[i][2];
        // wave-exclusive prefix within superblock (uniform per wave)
        float wB = 0.f;
        if (wv > 0) wB = b0;
        if (wv > 1) wB = fmaf(A256, wB, b1);
        if (wv > 2) wB = fmaf(A256, wB, b2);
        // this thread's entry state
        float f = fmaf(D4L, fmaf(DW, E, wB), eB[i]);

        int g = c0 + i * 1024 + 4 * tid;
        if (g < TLEN) {
            float4 a = *reinterpret_cast<const float4*>(arow + g);
            float4 m;
            f = fmaf(AC, f, BC * w[4 * i]);     m.x = fmaf(NL, f, a.x);
            f = fmaf(AC, f, BC * w[4 * i + 1]); m.y = fmaf(NL, f, a.y);
            f = fmaf(AC, f, BC * w[4 * i + 2]); m.z = fmaf(NL, f, a.z);
            f = fmaf(AC, f, BC * w[4 * i + 3]); m.w = fmaf(NL, f, a.w);
            *reinterpret_cast<float4*>(orow + g) = m;
            mx = fmaxf(mx, fmaxf(fmaxf(fabsf(m.x), fabsf(m.y)),
                                 fmaxf(fabsf(m.z), fabsf(m.w))));
        }
        // advance superblock entry: E' = 0.99^1024 * E + T_i
        float t = b0;
        t = fmaf(A256, t, b1);
        t = fmaf(A256, t, b2);
        t = fmaf(A256, t, sB[i][3]);
        E = fmaf(A1024, E, t);
    }

    // ---- block max -> global atomic ----
    #pragma unroll
    for (int d = 32; d >= 1; d >>= 1)
        mx = fmaxf(mx, __shfl_xor(mx, d, 64));
    if (lane == 0) sM[wv] = mx;
    __syncthreads();
    if (tid == 0) {
        float m = fmaxf(fmaxf(sM[0], sM[1]), fmaxf(sM[2], sM[3]));
        atomicMax(gmax, __float_as_uint(m));   // values >= 0: uint order == float order
    }
}

__global__ __launch_bounds__(256)
void scale_kernel(float* __restrict__ out, const unsigned int* __restrict__ gmax, int n4)
{
    const float m = __uint_as_float(*gmax);
    const float s = (m > 1.0f) ? (1.0f / m) : 1.0f;
    float4* p = reinterpret_cast<float4*>(out);
    int i = blockIdx.x * blockDim.x + threadIdx.x;
    const int stride = gridDim.x * blockDim.x;
    for (; i < n4; i += stride) {
        float4 v = p[i];
        v.x *= s; v.y *= s; v.z *= s; v.w *= s;
        p[i] = v;
    }
}

extern "C" void kernel_launch(void* const* d_in, const int* in_sizes, int n_in,
                              void* d_out, int out_size, void* d_ws, size_t ws_size,
                              hipStream_t stream)
{
    const float* waveform = (const float*)d_in[0];
    const float* white    = (const float*)d_in[1];
    float* out            = (float*)d_out;
    unsigned int* gmax    = (unsigned int*)d_ws;

    hipLaunchKernelGGL(init_max_kernel, dim3(1), dim3(1), 0, stream, gmax);

    dim3 grid(NCHUNK, CHANNELS);           // 27 x 256 blocks
    hipLaunchKernelGGL(pink_mix_kernel, grid, dim3(NT), 0, stream,
                       waveform, white, out, gmax);

    const int n4 = out_size / 4;           // 14,112,000 float4s
    hipLaunchKernelGGL(scale_kernel, dim3(3072), dim3(256), 0, stream,
                       out, gmax, n4);
}

// Round 4
// 233.502 us; speedup vs baseline: 2.9657x; 1.0054x over previous
//
#include <hip/hip_runtime.h>

// EnvironmentalAugmentations: pink = AR(1) scan of white noise (a=0.99, b=0.01),
// mixed = waveform + 0.05*pink, out = mixed / max(|mixed|) if max > 1 else mixed.
// Shapes: (256 channels, 220500 samples), f32 in / f32 out.
//
// Chunked-independence: 0.99^1024 = 3.4e-5 -> each 8192-sample chunk computed
// independently with a 1024-sample warm-up (truncation error < 1e-6 in output).
// Entry-state trick: chunk 0 uses E = w[0]; exact because a + b = 1.
//
// R1: LDS-staged -> latency-bound (41% occ, 12% VALU, 175 us).
// R2: per-thread-contiguous loads -> uncoalesced, FETCH 1.68 GB, 625 us.
// R3: coalesced superblock scan, but launch_bounds(256,6) -> 40 VGPR -> epilogue
//     loads serialized (load->wait->use x8), 173 us at 17% HBM.
// R4: launch_bounds(256,4) (128 VGPR cap) + prefetch ALL loads (white, warm-up,
//     waveform) before the scan/barrier -> latency hidden by ILP.

#define TLEN 220500
#define CHANNELS 256

constexpr int CL   = 8192;          // samples per block
constexpr int NT   = 256;           // threads per block
constexpr int NSB  = 8;             // superblocks per chunk (1024 samples each)
constexpr int NCHUNK = (TLEN + CL - 1) / CL;   // 27

constexpr float AC = 0.99f;
constexpr float BC = 0.01f;
constexpr float NL = 0.05f;

constexpr double dpow(double a, int n) { double r = 1.0; for (int i = 0; i < n; ++i) r *= a; return r; }

// Geometric Hillis-Steele step multipliers, 4-sample granularity: 0.99^(4d)
constexpr float WP0 = (float)dpow(0.99, 4 * 1);
constexpr float WP1 = (float)dpow(0.99, 4 * 2);
constexpr float WP2 = (float)dpow(0.99, 4 * 4);
constexpr float WP3 = (float)dpow(0.99, 4 * 8);
constexpr float WP4 = (float)dpow(0.99, 4 * 16);
constexpr float WP5 = (float)dpow(0.99, 4 * 32);
constexpr float A256  = (float)dpow(0.99, 256);    // wave span (64 lanes x 4)
constexpr float A1024 = (float)dpow(0.99, 1024);   // superblock span
constexpr float L2A4   = -0.05799827878044602f;    // 4   * log2(0.99)
constexpr float L2A256 = -3.7118898419485456f;     // 256 * log2(0.99)

__global__ void init_max_kernel(unsigned int* gmax) { *gmax = 0u; }

__device__ __forceinline__ float wave_scan4(float f, int lane) {
    // inclusive geometric scan across 64 lanes, 4 samples per lane
    { float o = __shfl_up(f, 1,  64); if (lane >= 1)  f = fmaf(WP0, o, f); }
    { float o = __shfl_up(f, 2,  64); if (lane >= 2)  f = fmaf(WP1, o, f); }
    { float o = __shfl_up(f, 4,  64); if (lane >= 4)  f = fmaf(WP2, o, f); }
    { float o = __shfl_up(f, 8,  64); if (lane >= 8)  f = fmaf(WP3, o, f); }
    { float o = __shfl_up(f, 16, 64); if (lane >= 16) f = fmaf(WP4, o, f); }
    { float o = __shfl_up(f, 32, 64); if (lane >= 32) f = fmaf(WP5, o, f); }
    return f;
}

__global__ __launch_bounds__(NT, 4)
void pink_mix_kernel(const float* __restrict__ waveform,
                     const float* __restrict__ white,
                     float* __restrict__ out,
                     unsigned int* __restrict__ gmax)
{
    __shared__ float sB[NSB + 1][4];   // wave totals: 8 main superblocks + warm-up
    __shared__ float sM[4];            // per-wave max
    __shared__ float sW0;              // first white sample of chunk

    const int chunk = blockIdx.x;
    const int ch    = blockIdx.y;
    const int c0    = chunk * CL;
    const size_t rowoff = (size_t)ch * TLEN;
    const float* __restrict__ wrow = white + rowoff;
    const float* __restrict__ arow = waveform + rowoff;
    float* __restrict__ orow = out + rowoff;

    const int tid  = threadIdx.x;
    const int lane = tid & 63;
    const int wv   = tid >> 6;

    // ---- PREFETCH EVERYTHING: 8 white + 8 waveform float4 (coalesced),
    //      plus the warm-up float4. All issued before any use/barrier. ----
    float4 wf[NSB];   // white
    float4 af[NSB];   // waveform
    #pragma unroll
    for (int i = 0; i < NSB; ++i) {
        int g = c0 + i * 1024 + 4 * tid;
        if (g < TLEN) {
            wf[i] = *reinterpret_cast<const float4*>(wrow + g);   // TLEN%4==0
            af[i] = *reinterpret_cast<const float4*>(arow + g);
        } else {
            wf[i] = make_float4(0.f, 0.f, 0.f, 0.f);
            af[i] = make_float4(0.f, 0.f, 0.f, 0.f);
        }
    }
    float4 wu = make_float4(0.f, 0.f, 0.f, 0.f);
    if (chunk > 0)
        wu = *reinterpret_cast<const float4*>(wrow + (c0 - 1024) + 4 * tid);

    // ---- per-superblock: 4-sample serial + wave scan; lane-excl kept in regs ----
    float eB[NSB];
    #pragma unroll
    for (int i = 0; i < NSB; ++i) {
        float f = BC * wf[i].x;
        f = fmaf(AC, f, BC * wf[i].y);
        f = fmaf(AC, f, BC * wf[i].z);
        f = fmaf(AC, f, BC * wf[i].w);
        float pB = wave_scan4(f, lane);
        float e  = __shfl_up(pB, 1, 64);
        eB[i] = (lane == 0) ? 0.f : e;
        if (lane == 63) sB[i][wv] = pB;
    }

    // ---- warm-up superblock [c0-1024, c0) ----
    if (chunk > 0) {
        float f = BC * wu.x;
        f = fmaf(AC, f, BC * wu.y);
        f = fmaf(AC, f, BC * wu.z);
        f = fmaf(AC, f, BC * wu.w);
        float pB = wave_scan4(f, lane);
        if (lane == 63) sB[NSB][wv] = pB;
    }
    if (tid == 0) sW0 = wf[0].x;
    __syncthreads();

    // ---- chunk entry state (chunk 0: E = w[0]; exact since a+b=1) ----
    float E;
    if (chunk > 0) {
        float t = sB[NSB][0];
        t = fmaf(A256, t, sB[NSB][1]);
        t = fmaf(A256, t, sB[NSB][2]);
        t = fmaf(A256, t, sB[NSB][3]);
        E = t;
    } else {
        E = sW0;
    }

    // per-thread decay factors
    const float D4L = __builtin_exp2f((float)lane * L2A4);   // 0.99^(4*lane)
    const float DW  = __builtin_exp2f((float)wv   * L2A256); // 0.99^(256*wv)

    // ---- per-superblock: entry state, rescan, fused mix + store + max ----
    float mx = 0.f;
    #pragma unroll
    for (int i = 0; i < NSB; ++i) {
        const float b0 = sB[i][0], b1 = sB[i][1], b2 = sB[i][2];
        // wave-exclusive prefix within superblock (uniform per wave)
        float wB = 0.f;
        if (wv > 0) wB = b0;
        if (wv > 1) wB = fmaf(A256, wB, b1);
        if (wv > 2) wB = fmaf(A256, wB, b2);
        // this thread's entry state
        float f = fmaf(D4L, fmaf(DW, E, wB), eB[i]);

        int g = c0 + i * 1024 + 4 * tid;
        if (g < TLEN) {
            float4 m;
            f = fmaf(AC, f, BC * wf[i].x); m.x = fmaf(NL, f, af[i].x);
            f = fmaf(AC, f, BC * wf[i].y); m.y = fmaf(NL, f, af[i].y);
            f = fmaf(AC, f, BC * wf[i].z); m.z = fmaf(NL, f, af[i].z);
            f = fmaf(AC, f, BC * wf[i].w); m.w = fmaf(NL, f, af[i].w);
            *reinterpret_cast<float4*>(orow + g) = m;
            mx = fmaxf(mx, fmaxf(fmaxf(fabsf(m.x), fabsf(m.y)),
                                 fmaxf(fabsf(m.z), fabsf(m.w))));
        }
        // advance superblock entry: E' = 0.99^1024 * E + T_i
        float t = b0;
        t = fmaf(A256, t, b1);
        t = fmaf(A256, t, b2);
        t = fmaf(A256, t, sB[i][3]);
        E = fmaf(A1024, E, t);
    }

    // ---- block max -> global atomic ----
    #pragma unroll
    for (int d = 32; d >= 1; d >>= 1)
        mx = fmaxf(mx, __shfl_xor(mx, d, 64));
    if (lane == 0) sM[wv] = mx;
    __syncthreads();
    if (tid == 0) {
        float m = fmaxf(fmaxf(sM[0], sM[1]), fmaxf(sM[2], sM[3]));
        atomicMax(gmax, __float_as_uint(m));   // values >= 0: uint order == float order
    }
}

__global__ __launch_bounds__(256)
void scale_kernel(float* __restrict__ out, const unsigned int* __restrict__ gmax, int n4)
{
    const float m = __uint_as_float(*gmax);
    const float s = (m > 1.0f) ? (1.0f / m) : 1.0f;
    float4* p = reinterpret_cast<float4*>(out);
    int i = blockIdx.x * blockDim.x + threadIdx.x;
    const int stride = gridDim.x * blockDim.x;
    for (; i < n4; i += stride) {
        float4 v = p[i];
        v.x *= s; v.y *= s; v.z *= s; v.w *= s;
        p[i] = v;
    }
}

extern "C" void kernel_launch(void* const* d_in, const int* in_sizes, int n_in,
                              void* d_out, int out_size, void* d_ws, size_t ws_size,
                              hipStream_t stream)
{
    const float* waveform = (const float*)d_in[0];
    const float* white    = (const float*)d_in[1];
    float* out            = (float*)d_out;
    unsigned int* gmax    = (unsigned int*)d_ws;

    hipLaunchKernelGGL(init_max_kernel, dim3(1), dim3(1), 0, stream, gmax);

    dim3 grid(NCHUNK, CHANNELS);           // 27 x 256 blocks
    hipLaunchKernelGGL(pink_mix_kernel, grid, dim3(NT), 0, stream,
                       waveform, white, out, gmax);

    const int n4 = out_size / 4;           // 14,112,000 float4s
    hipLaunchKernelGGL(scale_kernel, dim3(3072), dim3(256), 0, stream,
                       out, gmax, n4);
}

// Round 5
// 231.351 us; speedup vs baseline: 2.9933x; 1.0093x over previous
//
#include <hip/hip_runtime.h>

// EnvironmentalAugmentations: pink = AR(1) scan of white noise (a=0.99, b=0.01),
// mixed = waveform + 0.05*pink, out = mixed / max(|mixed|) if max > 1 else mixed.
// Shapes: (256 channels, 220500 samples), f32 in / f32 out.
//
// Chunked-independence: 0.99^1024 = 3.4e-5 -> each 8192-sample chunk computed
// independently with a 1024-sample warm-up (truncation error < 1e-6 in output).
// Entry-state trick: chunk 0 uses E = w[0]; exact because a + b = 1.
//
// R1: LDS-staged -> 175 us.  R2: uncoalesced -> 625 us.  R3: coalesced superblock
// scan -> 173 us.  R4: +prefetch/128-VGPR cap -> 170 us (compiler sank loads;
// no change). R1/R3/R4 all ~170-175 us despite different structures => common
// limiter suspected: 6912 same-address device-scope atomicMax (one LLC line).
// R5: per-block max -> plain store into ws array + tiny reduce kernel. No hot
// atomic anywhere.

#define TLEN 220500
#define CHANNELS 256

constexpr int CL   = 8192;          // samples per block
constexpr int NT   = 256;           // threads per block
constexpr int NSB  = 8;             // superblocks per chunk (1024 samples each)
constexpr int NCHUNK = (TLEN + CL - 1) / CL;   // 27
constexpr int NBLK = NCHUNK * CHANNELS;        // 6912 pink_mix blocks

constexpr float AC = 0.99f;
constexpr float BC = 0.01f;
constexpr float NL = 0.05f;

constexpr double dpow(double a, int n) { double r = 1.0; for (int i = 0; i < n; ++i) r *= a; return r; }

// Geometric Hillis-Steele step multipliers, 4-sample granularity: 0.99^(4d)
constexpr float WP0 = (float)dpow(0.99, 4 * 1);
constexpr float WP1 = (float)dpow(0.99, 4 * 2);
constexpr float WP2 = (float)dpow(0.99, 4 * 4);
constexpr float WP3 = (float)dpow(0.99, 4 * 8);
constexpr float WP4 = (float)dpow(0.99, 4 * 16);
constexpr float WP5 = (float)dpow(0.99, 4 * 32);
constexpr float A256  = (float)dpow(0.99, 256);    // wave span (64 lanes x 4)
constexpr float A1024 = (float)dpow(0.99, 1024);   // superblock span
constexpr float L2A4   = -0.05799827878044602f;    // 4   * log2(0.99)
constexpr float L2A256 = -3.7118898419485456f;     // 256 * log2(0.99)

__global__ void init_max_kernel(unsigned int* gmax) { *gmax = 0u; }

__device__ __forceinline__ float wave_scan4(float f, int lane) {
    // inclusive geometric scan across 64 lanes, 4 samples per lane
    { float o = __shfl_up(f, 1,  64); if (lane >= 1)  f = fmaf(WP0, o, f); }
    { float o = __shfl_up(f, 2,  64); if (lane >= 2)  f = fmaf(WP1, o, f); }
    { float o = __shfl_up(f, 4,  64); if (lane >= 4)  f = fmaf(WP2, o, f); }
    { float o = __shfl_up(f, 8,  64); if (lane >= 8)  f = fmaf(WP3, o, f); }
    { float o = __shfl_up(f, 16, 64); if (lane >= 16) f = fmaf(WP4, o, f); }
    { float o = __shfl_up(f, 32, 64); if (lane >= 32) f = fmaf(WP5, o, f); }
    return f;
}

// USE_ATOMIC=1 is the fallback path (ws too small): old atomicMax into gmax.
template <int USE_ATOMIC>
__global__ __launch_bounds__(NT, 4)
void pink_mix_kernel(const float* __restrict__ waveform,
                     const float* __restrict__ white,
                     float* __restrict__ out,
                     unsigned int* __restrict__ gmax,
                     float* __restrict__ blockmax)
{
    __shared__ float sB[NSB + 1][4];   // wave totals: 8 main superblocks + warm-up
    __shared__ float sM[4];            // per-wave max
    __shared__ float sW0;              // first white sample of chunk

    const int chunk = blockIdx.x;
    const int ch    = blockIdx.y;
    const int c0    = chunk * CL;
    const size_t rowoff = (size_t)ch * TLEN;
    const float* __restrict__ wrow = white + rowoff;
    const float* __restrict__ arow = waveform + rowoff;
    float* __restrict__ orow = out + rowoff;

    const int tid  = threadIdx.x;
    const int lane = tid & 63;
    const int wv   = tid >> 6;

    // ---- coalesced loads: 8 white + 8 waveform float4 + warm-up float4 ----
    float4 wf[NSB];   // white
    float4 af[NSB];   // waveform
    #pragma unroll
    for (int i = 0; i < NSB; ++i) {
        int g = c0 + i * 1024 + 4 * tid;
        if (g < TLEN) {
            wf[i] = *reinterpret_cast<const float4*>(wrow + g);   // TLEN%4==0
            af[i] = *reinterpret_cast<const float4*>(arow + g);
        } else {
            wf[i] = make_float4(0.f, 0.f, 0.f, 0.f);
            af[i] = make_float4(0.f, 0.f, 0.f, 0.f);
        }
    }
    float4 wu = make_float4(0.f, 0.f, 0.f, 0.f);
    if (chunk > 0)
        wu = *reinterpret_cast<const float4*>(wrow + (c0 - 1024) + 4 * tid);

    // ---- per-superblock: 4-sample serial + wave scan; lane-excl kept in regs ----
    float eB[NSB];
    #pragma unroll
    for (int i = 0; i < NSB; ++i) {
        float f = BC * wf[i].x;
        f = fmaf(AC, f, BC * wf[i].y);
        f = fmaf(AC, f, BC * wf[i].z);
        f = fmaf(AC, f, BC * wf[i].w);
        float pB = wave_scan4(f, lane);
        float e  = __shfl_up(pB, 1, 64);
        eB[i] = (lane == 0) ? 0.f : e;
        if (lane == 63) sB[i][wv] = pB;
    }

    // ---- warm-up superblock [c0-1024, c0) ----
    if (chunk > 0) {
        float f = BC * wu.x;
        f = fmaf(AC, f, BC * wu.y);
        f = fmaf(AC, f, BC * wu.z);
        f = fmaf(AC, f, BC * wu.w);
        float pB = wave_scan4(f, lane);
        if (lane == 63) sB[NSB][wv] = pB;
    }
    if (tid == 0) sW0 = wf[0].x;
    __syncthreads();

    // ---- chunk entry state (chunk 0: E = w[0]; exact since a+b=1) ----
    float E;
    if (chunk > 0) {
        float t = sB[NSB][0];
        t = fmaf(A256, t, sB[NSB][1]);
        t = fmaf(A256, t, sB[NSB][2]);
        t = fmaf(A256, t, sB[NSB][3]);
        E = t;
    } else {
        E = sW0;
    }

    // per-thread decay factors
    const float D4L = __builtin_exp2f((float)lane * L2A4);   // 0.99^(4*lane)
    const float DW  = __builtin_exp2f((float)wv   * L2A256); // 0.99^(256*wv)

    // ---- per-superblock: entry state, rescan, fused mix + store + max ----
    float mx = 0.f;
    #pragma unroll
    for (int i = 0; i < NSB; ++i) {
        const float b0 = sB[i][0], b1 = sB[i][1], b2 = sB[i][2];
        // wave-exclusive prefix within superblock (uniform per wave)
        float wB = 0.f;
        if (wv > 0) wB = b0;
        if (wv > 1) wB = fmaf(A256, wB, b1);
        if (wv > 2) wB = fmaf(A256, wB, b2);
        // this thread's entry state
        float f = fmaf(D4L, fmaf(DW, E, wB), eB[i]);

        int g = c0 + i * 1024 + 4 * tid;
        if (g < TLEN) {
            float4 m;
            f = fmaf(AC, f, BC * wf[i].x); m.x = fmaf(NL, f, af[i].x);
            f = fmaf(AC, f, BC * wf[i].y); m.y = fmaf(NL, f, af[i].y);
            f = fmaf(AC, f, BC * wf[i].z); m.z = fmaf(NL, f, af[i].z);
            f = fmaf(AC, f, BC * wf[i].w); m.w = fmaf(NL, f, af[i].w);
            *reinterpret_cast<float4*>(orow + g) = m;
            mx = fmaxf(mx, fmaxf(fmaxf(fabsf(m.x), fabsf(m.y)),
                                 fmaxf(fabsf(m.z), fabsf(m.w))));
        }
        // advance superblock entry: E' = 0.99^1024 * E + T_i
        float t = b0;
        t = fmaf(A256, t, b1);
        t = fmaf(A256, t, b2);
        t = fmaf(A256, t, sB[i][3]);
        E = fmaf(A1024, E, t);
    }

    // ---- block max: plain store (no hot atomic) ----
    #pragma unroll
    for (int d = 32; d >= 1; d >>= 1)
        mx = fmaxf(mx, __shfl_xor(mx, d, 64));
    if (lane == 0) sM[wv] = mx;
    __syncthreads();
    if (tid == 0) {
        float m = fmaxf(fmaxf(sM[0], sM[1]), fmaxf(sM[2], sM[3]));
        if (USE_ATOMIC) {
            atomicMax(gmax, __float_as_uint(m));
        } else {
            blockmax[ch * NCHUNK + chunk] = m;
        }
    }
}

// single-block reduce: 6912 per-block maxima -> gmax (uint float-bits)
__global__ __launch_bounds__(256)
void reduce_max_kernel(const float* __restrict__ blockmax, unsigned int* __restrict__ gmax)
{
    __shared__ float sM[4];
    const int tid  = threadIdx.x;
    const int lane = tid & 63;
    const int wv   = tid >> 6;
    float mx = 0.f;
    for (int i = tid; i < NBLK; i += 256)
        mx = fmaxf(mx, blockmax[i]);
    #pragma unroll
    for (int d = 32; d >= 1; d >>= 1)
        mx = fmaxf(mx, __shfl_xor(mx, d, 64));
    if (lane == 0) sM[wv] = mx;
    __syncthreads();
    if (tid == 0)
        *gmax = __float_as_uint(fmaxf(fmaxf(sM[0], sM[1]), fmaxf(sM[2], sM[3])));
}

__global__ __launch_bounds__(256)
void scale_kernel(float* __restrict__ out, const unsigned int* __restrict__ gmax, int n4)
{
    const float m = __uint_as_float(*gmax);
    const float s = (m > 1.0f) ? (1.0f / m) : 1.0f;
    float4* p = reinterpret_cast<float4*>(out);
    int i = blockIdx.x * blockDim.x + threadIdx.x;
    const int stride = gridDim.x * blockDim.x;
    for (; i < n4; i += stride) {
        float4 v = p[i];
        v.x *= s; v.y *= s; v.z *= s; v.w *= s;
        p[i] = v;
    }
}

extern "C" void kernel_launch(void* const* d_in, const int* in_sizes, int n_in,
                              void* d_out, int out_size, void* d_ws, size_t ws_size,
                              hipStream_t stream)
{
    const float* waveform = (const float*)d_in[0];
    const float* white    = (const float*)d_in[1];
    float* out            = (float*)d_out;

    // ws layout: [0] uint gmax (256B reserved), then NBLK floats of block maxima
    unsigned int* gmax = (unsigned int*)d_ws;
    float* blockmax    = (float*)((char*)d_ws + 256);
    const bool ws_ok   = ws_size >= 256 + (size_t)NBLK * sizeof(float);

    dim3 grid(NCHUNK, CHANNELS);           // 27 x 256 blocks
    const int n4 = out_size / 4;           // 14,112,000 float4s

    if (ws_ok) {
        hipLaunchKernelGGL((pink_mix_kernel<0>), grid, dim3(NT), 0, stream,
                           waveform, white, out, gmax, blockmax);
        hipLaunchKernelGGL(reduce_max_kernel, dim3(1), dim3(256), 0, stream,
                           blockmax, gmax);
    } else {
        hipLaunchKernelGGL(init_max_kernel, dim3(1), dim3(1), 0, stream, gmax);
        hipLaunchKernelGGL((pink_mix_kernel<1>), grid, dim3(NT), 0, stream,
                           waveform, white, out, gmax, blockmax);
    }
    hipLaunchKernelGGL(scale_kernel, dim3(3072), dim3(256), 0, stream,
                       out, gmax, n4);
}